// Round 1
// 723.126 us; speedup vs baseline: 1.0196x; 1.0196x over previous
//
#include <hip/hip_runtime.h>
#include <hip/hip_bf16.h>
#include <stdint.h>

// CrossAttention: B=16 N=4096 M=77 H=8 D=64 QDIM=1024 CDIM=768 INNER=512
// fp32 interface, bf16 MFMA internals, fp32 accumulation.

typedef unsigned short u16;
typedef __bf16 bf16x8 __attribute__((ext_vector_type(8)));
typedef float f32x4 __attribute__((ext_vector_type(4)));

__device__ __forceinline__ void gld_lds16(const void* g, void* l) {
  __builtin_amdgcn_global_load_lds(
      (const __attribute__((address_space(1))) unsigned int*)g,
      (__attribute__((address_space(3))) unsigned int*)l, 16, 0, 0);
}

__device__ __forceinline__ u16 f2bf(float f) {
  __hip_bfloat16 h = __float2bfloat16(f);
  return *reinterpret_cast<u16*>(&h);
}

// out[n*K+k] = bf16(in[k*N+n])  (in: K x N fp32 row-major; out: N x K bf16)
__global__ void wtrans(const float* __restrict__ in, u16* __restrict__ out,
                       int K, int N) {
  int idx = blockIdx.x * 256 + threadIdx.x;
  if (idx < K * N) {
    int n = idx / K, k = idx - n * K;
    out[idx] = f2bf(in[k * N + n]);
  }
}

// vt_all[bh][d][m] = v[b][m][h][d], m clamped to 76 for m in [77,96)
__global__ void vtrans(const u16* __restrict__ kv_all, u16* __restrict__ vt_all) {
  int idx = blockIdx.x * 256 + threadIdx.x;
  if (idx < 16 * 8 * 64 * 96) {
    int m = idx % 96;
    int t = idx / 96;
    int d = t & 63;
    int bh = t >> 6;
    int b = bh >> 3, h = bh & 7;
    int mg = m < 77 ? m : 76;
    vt_all[idx] = kv_all[(size_t)(b * 77 + mg) * 1024 + 512 + h * 64 + d];
  }
}

// ---------- 128x128-tile GEMM (known-good; used for small kv GEMM) ----------
template <bool A_F32, bool C_F32>
__global__ __launch_bounds__(256, 2) void gemm_bt(
    const void* __restrict__ Av, const u16* __restrict__ BT,
    void* __restrict__ Cv, const float* __restrict__ bias,
    int Mr, int K, int Nc) {
  __shared__ u16 Al[128 * 32 * (A_F32 ? 2 : 1)];
  __shared__ u16 Bl[128 * 32];
  const int tid = threadIdx.x;
  const int lane = tid & 63;
  const int wave = tid >> 6;
  const int mlane = lane & 15;
  const int quad = lane >> 4;
  const int m0 = blockIdx.y * 128;
  const int n0 = blockIdx.x * 128;
  const int wm = (wave & 1) * 64;
  const int wn = (wave >> 1) * 64;

  f32x4 acc[4][4];
#pragma unroll
  for (int i = 0; i < 4; ++i)
#pragma unroll
    for (int j = 0; j < 4; ++j) acc[i][j] = (f32x4){0.f, 0.f, 0.f, 0.f};

  const int o0 = tid * 16;

  for (int k0 = 0; k0 < K; k0 += 32) {
    if (A_F32) {
#pragma unroll
      for (int r = 0; r < 4; ++r) {
        const int o = r * 4096 + o0;
        const int row = o >> 7;
        const int colb = o & 127;
        int rg = m0 + row;
        rg = rg < Mr ? rg : (Mr - 1);
        gld_lds16((const char*)Av + ((size_t)rg * K + k0) * 4 + colb,
                  (char*)Al + o);
      }
    } else {
#pragma unroll
      for (int r = 0; r < 2; ++r) {
        const int o = r * 4096 + o0;
        const int row = o >> 6;
        const int colb = o & 63;
        int rg = m0 + row;
        rg = rg < Mr ? rg : (Mr - 1);
        gld_lds16((const char*)Av + ((size_t)rg * K + k0) * 2 + colb,
                  (char*)Al + o);
      }
    }
#pragma unroll
    for (int r = 0; r < 2; ++r) {
      const int o = r * 4096 + o0;
      const int row = o >> 6;
      const int colb = o & 63;
      gld_lds16((const char*)BT + ((size_t)(n0 + row) * K + k0) * 2 + colb,
                (char*)Bl + o);
    }
    __syncthreads();

    bf16x8 af[4], bfr[4];
    if (A_F32) {
      const float* Af = (const float*)Al;
#pragma unroll
      for (int i = 0; i < 4; ++i) {
        const float* ar = Af + (wm + i * 16 + mlane) * 32 + quad * 8;
        f32x4 x0 = *(const f32x4*)ar;
        f32x4 x1 = *(const f32x4*)(ar + 4);
        bf16x8 t;
#pragma unroll
        for (int e = 0; e < 4; ++e) {
          u16 lo = f2bf(x0[e]);
          u16 hi = f2bf(x1[e]);
          t[e] = *reinterpret_cast<__bf16*>(&lo);
          t[e + 4] = *reinterpret_cast<__bf16*>(&hi);
        }
        af[i] = t;
      }
    } else {
      const u16* Ab = (const u16*)Al;
#pragma unroll
      for (int i = 0; i < 4; ++i)
        af[i] = *(const bf16x8*)(Ab + (wm + i * 16 + mlane) * 32 + quad * 8);
    }
#pragma unroll
    for (int j = 0; j < 4; ++j)
      bfr[j] = *(const bf16x8*)(Bl + (wn + j * 16 + mlane) * 32 + quad * 8);
#pragma unroll
    for (int i = 0; i < 4; ++i)
#pragma unroll
      for (int j = 0; j < 4; ++j)
        acc[i][j] = __builtin_amdgcn_mfma_f32_16x16x32_bf16(af[i], bfr[j],
                                                            acc[i][j], 0, 0, 0);
    __syncthreads();
  }

#pragma unroll
  for (int j = 0; j < 4; ++j) {
    const int col = n0 + wn + j * 16 + mlane;
    const float bv = C_F32 ? bias[col] : 0.f;
#pragma unroll
    for (int i = 0; i < 4; ++i) {
      const int rb = m0 + wm + i * 16 + quad * 4;
#pragma unroll
      for (int r = 0; r < 4; ++r) {
        const int row = rb + r;
        if (row < Mr) {
          if (C_F32)
            ((float*)Cv)[(size_t)row * Nc + col] = acc[i][j][r] + bv;
          else
            ((u16*)Cv)[(size_t)row * Nc + col] = f2bf(acc[i][j][r]);
        }
      }
    }
  }
}

// ---------- deep-pipelined 256x128 GEMM (3-buffer ring, counted vmcnt) ------
// BM=256 BN=128 BK=64, 8 waves (4Mx2N, wave tile 64x64), 144 KiB LDS.
// Requires M%256==0, N%128==0, K%64==0, K>=128.
// LDS slot layout: A [256][64] bf16 (32 KiB) | B [128][64] bf16 (16 KiB),
// both XOR-swizzled: elem(r,c) at byte r*128 + ((c*2) ^ ((r&7)<<4)).
// Swizzle applied on the GLOBAL source address (linear gload_lds dest).
// Pipeline: while computing tile t, tile t+1 is resident, tile t+2 in flight;
// per-tile wait is vmcnt(6) (bf16 A) / vmcnt(2)+ds_write (fp32 A) — never 0.

#define DG_STAGE_A_BF16(t_, sl_)                                              \
  {                                                                           \
    const char* ab_ =                                                         \
        (const char*)Av + (size_t)2 * ((size_t)m0 * K + (t_) * 64);           \
    char* lb_ = lds + (sl_)*DG_BUF;                                           \
    _Pragma("unroll") for (int c_ = 0; c_ < 4; ++c_) {                        \
      gld_lds16(ab_ + (size_t)2 * (size_t)(c_ * 64 + arow) * K + asrc,        \
                lb_ + c_ * 8192 + tid * 16);                                  \
    }                                                                         \
  }

#define DG_STAGE_B(t_, sl_)                                                   \
  {                                                                           \
    const char* bb_ =                                                         \
        (const char*)BT + (size_t)2 * ((size_t)n0 * K + (t_) * 64);           \
    char* lb_ = lds + (sl_)*DG_BUF + 32768;                                   \
    _Pragma("unroll") for (int c_ = 0; c_ < 2; ++c_) {                        \
      gld_lds16(bb_ + (size_t)2 * (size_t)(c_ * 64 + arow) * K + asrc,        \
                lb_ + c_ * 8192 + tid * 16);                                  \
    }                                                                         \
  }

#define DG_LOAD_A_F32(t_)                                                     \
  {                                                                           \
    const float* af_ = (const float*)Av + (size_t)m0 * K + (t_) * 64;         \
    _Pragma("unroll") for (int c_ = 0; c_ < 4; ++c_) {                        \
      const float* s_ = af_ + (size_t)(c_ * 64 + arow) * K + (asrc >> 1);     \
      sa[2 * c_] = *(const f32x4*)s_;                                         \
      sa[2 * c_ + 1] = *(const f32x4*)(s_ + 4);                               \
    }                                                                         \
  }

#define DG_WRITE_A_F32(sl_)                                                   \
  {                                                                           \
    char* lb_ = lds + (sl_)*DG_BUF;                                           \
    _Pragma("unroll") for (int c_ = 0; c_ < 4; ++c_) {                        \
      bf16x8 w_;                                                              \
      _Pragma("unroll") for (int e_ = 0; e_ < 4; ++e_) {                      \
        u16 lo_ = f2bf(sa[2 * c_][e_]);                                       \
        u16 hi_ = f2bf(sa[2 * c_ + 1][e_]);                                   \
        w_[e_] = *reinterpret_cast<__bf16*>(&lo_);                            \
        w_[e_ + 4] = *reinterpret_cast<__bf16*>(&hi_);                        \
      }                                                                       \
      *(bf16x8*)(lb_ + c_ * 8192 + tid * 16) = w_;                            \
    }                                                                         \
  }

template <bool A_F32, bool C_F32, int NXL2>
__global__ __launch_bounds__(512, 2) void gemm_deep(
    const void* __restrict__ Av, const u16* __restrict__ BT,
    void* __restrict__ Cv, const float* __restrict__ bias,
    const int K, const int Nc) {
  constexpr int DG_BUF = 49152;
  __shared__ __align__(16) char lds[3 * DG_BUF];

  const int tid = threadIdx.x;
  const int lane = tid & 63;
  const int wave = tid >> 6;
  const int mlane = lane & 15;
  const int quad = lane >> 4;
  const int wm = (wave >> 1) * 64;
  const int wn = (wave & 1) * 64;
  const int rswz = (mlane & 7) << 4;  // ds_read XOR (matches source XOR)

  // staging geometry: 8 threads per 128B row, XOR-permuted 16B chunks
  const int arow = tid >> 3;                        // row within 64-row group
  const int asrc = ((tid & 7) * 16) ^ ((arow & 7) << 4);  // src byte col

  // XCD-bijective block swizzle; same-XCD blocks run n-fastest (A-stripe L2 reuse)
  const int nwg = 256 << NXL2;
  const int wg = blockIdx.y * (1 << NXL2) + blockIdx.x;
  const int swz = (wg & 7) * (nwg >> 3) + (wg >> 3);
  const int m0 = (swz >> NXL2) * 256;
  const int n0 = (swz & ((1 << NXL2) - 1)) * 128;

  const int nt = K >> 6;

  f32x4 acc[4][4];
#pragma unroll
  for (int i = 0; i < 4; ++i)
#pragma unroll
    for (int j = 0; j < 4; ++j) acc[i][j] = (f32x4){0.f, 0.f, 0.f, 0.f};

  f32x4 sa[8];  // fp32-A staging regs (dead code when !A_F32)

  // ---- prologue: tiles 0,1 into slots 0,1; tile-0 guaranteed resident ----
  if (A_F32) {
    DG_LOAD_A_F32(0);
    DG_STAGE_B(0, 0);
    asm volatile("s_waitcnt vmcnt(2)" ::: "memory");
    __builtin_amdgcn_sched_barrier(0);
    DG_WRITE_A_F32(0);
    DG_LOAD_A_F32(1);
    DG_STAGE_B(1, 1);
    asm volatile("s_waitcnt vmcnt(2)" ::: "memory");
    __builtin_amdgcn_sched_barrier(0);
    DG_WRITE_A_F32(1);
    asm volatile("s_waitcnt lgkmcnt(0)" ::: "memory");
  } else {
    DG_STAGE_A_BF16(0, 0);
    DG_STAGE_B(0, 0);
    DG_STAGE_A_BF16(1, 1);
    DG_STAGE_B(1, 1);
    asm volatile("s_waitcnt vmcnt(6)" ::: "memory");
  }
  __builtin_amdgcn_sched_barrier(0);
  __builtin_amdgcn_s_barrier();
  __builtin_amdgcn_sched_barrier(0);

  int slot = 0;
  for (int t = 0; t < nt; ++t) {
    const char* la = lds + slot * DG_BUF;
    const char* lb = la + 32768;
    const int t2 = t + 2;
    const bool do_stage = t2 < nt;
    const int s2 = (slot >= 1) ? slot - 1 : slot + 2;  // (t+2)%3

    // ---- phase 0: ds_read ks=0 frags; issue A-stage for t+2 ----
    bf16x8 a0[4], b0[4];
#pragma unroll
    for (int i = 0; i < 4; ++i)
      a0[i] = *(const bf16x8*)(la + (wm + i * 16 + mlane) * 128 +
                               ((quad * 16) ^ rswz));
#pragma unroll
    for (int j = 0; j < 4; ++j)
      b0[j] = *(const bf16x8*)(lb + (wn + j * 16 + mlane) * 128 +
                               ((quad * 16) ^ rswz));
    if (do_stage) {
      if (A_F32) {
        DG_LOAD_A_F32(t2);
      } else {
        DG_STAGE_A_BF16(t2, s2);
      }
    }
    __builtin_amdgcn_sched_barrier(0);
    __builtin_amdgcn_s_barrier();
    __builtin_amdgcn_sched_barrier(0);
    __builtin_amdgcn_s_setprio(1);
#pragma unroll
    for (int i = 0; i < 4; ++i)
#pragma unroll
      for (int j = 0; j < 4; ++j)
        acc[i][j] = __builtin_amdgcn_mfma_f32_16x16x32_bf16(a0[i], b0[j],
                                                            acc[i][j], 0, 0, 0);
    __builtin_amdgcn_s_setprio(0);

    // ---- phase 1: ds_read ks=1 frags; issue B-stage for t+2 ----
    bf16x8 a1[4], b1[4];
#pragma unroll
    for (int i = 0; i < 4; ++i)
      a1[i] = *(const bf16x8*)(la + (wm + i * 16 + mlane) * 128 +
                               ((64 + quad * 16) ^ rswz));
#pragma unroll
    for (int j = 0; j < 4; ++j)
      b1[j] = *(const bf16x8*)(lb + (wn + j * 16 + mlane) * 128 +
                               ((64 + quad * 16) ^ rswz));
    if (do_stage) {
      DG_STAGE_B(t2, s2);
    }
    __builtin_amdgcn_sched_barrier(0);
    __builtin_amdgcn_s_barrier();
    __builtin_amdgcn_sched_barrier(0);
    __builtin_amdgcn_s_setprio(1);
#pragma unroll
    for (int i = 0; i < 4; ++i)
#pragma unroll
      for (int j = 0; j < 4; ++j)
        acc[i][j] = __builtin_amdgcn_mfma_f32_16x16x32_bf16(a1[i], b1[j],
                                                            acc[i][j], 0, 0, 0);
    __builtin_amdgcn_s_setprio(0);

    // ---- boundary: counted wait (tile t+1 resident; t+2 stays in flight) ----
    if (t + 1 < nt) {
      if (A_F32) {
        if (do_stage) {
          asm volatile("s_waitcnt vmcnt(2)" ::: "memory");
          __builtin_amdgcn_sched_barrier(0);
          DG_WRITE_A_F32(s2);
          asm volatile("s_waitcnt lgkmcnt(0)" ::: "memory");
        } else {
          asm volatile("s_waitcnt vmcnt(0)" ::: "memory");
        }
      } else {
        if (do_stage) {
          asm volatile("s_waitcnt vmcnt(6)" ::: "memory");
        } else {
          asm volatile("s_waitcnt vmcnt(0)" ::: "memory");
        }
      }
      __builtin_amdgcn_sched_barrier(0);
      __builtin_amdgcn_s_barrier();
      __builtin_amdgcn_sched_barrier(0);
    }
    slot = (slot == 2) ? 0 : slot + 1;
  }

  // ---- epilogue ----
#pragma unroll
  for (int j = 0; j < 4; ++j) {
    const int col = n0 + wn + j * 16 + mlane;
    const float bv = C_F32 ? bias[col] : 0.f;
#pragma unroll
    for (int i = 0; i < 4; ++i) {
      const int rb = m0 + wm + i * 16 + quad * 4;
#pragma unroll
      for (int r = 0; r < 4; ++r) {
        const size_t off = (size_t)(rb + r) * Nc + col;
        if (C_F32)
          ((float*)Cv)[off] = acc[i][j][r] + bv;
        else
          ((u16*)Cv)[off] = f2bf(acc[i][j][r]);
      }
    }
  }
}

// ---------- MFMA flash attention (unchanged) ----------
__global__ __launch_bounds__(256, 2) void attn_mfma(
    const u16* __restrict__ q_all,   // (B*4096, 512) bf16
    const u16* __restrict__ kv_all,  // (B*77, 1024) bf16: k | v
    const u16* __restrict__ vt_all,  // (B*H, 64, 96) bf16
    u16* __restrict__ o_all) {       // (B*4096, 512) bf16
  __shared__ u16 Ps[128 * 128];  // elem(row,col) at row*128 + swz(row,col)
  const int tid = threadIdx.x;
  const int lane = tid & 63;
  const int wave = tid >> 6;
  const int mlane = lane & 15;
  const int quad = lane >> 4;
  const int b = blockIdx.x >> 3;
  const int h = blockIdx.x & 7;
  const int n0 = blockIdx.y * 128;
  const int wm = wave * 32;

  const u16* qbase =
      q_all + ((size_t)(b * 4096 + n0 + wm)) * 512 + h * 64;
  bf16x8 aq[2][2];
#pragma unroll
  for (int i = 0; i < 2; ++i)
#pragma unroll
    for (int ks = 0; ks < 2; ++ks)
      aq[i][ks] = *(const bf16x8*)(qbase + (size_t)(i * 16 + mlane) * 512 +
                                   ks * 32 + quad * 8);

  bf16x8 bk[5][2];
#pragma unroll
  for (int j = 0; j < 5; ++j) {
    int m = j * 16 + mlane;
    m = m < 77 ? m : 76;
    const u16* kb = kv_all + ((size_t)(b * 77 + m)) * 1024 + h * 64;
#pragma unroll
    for (int ks = 0; ks < 2; ++ks)
      bk[j][ks] = *(const bf16x8*)(kb + ks * 32 + quad * 8);
  }

  f32x4 S[2][5];
#pragma unroll
  for (int i = 0; i < 2; ++i)
#pragma unroll
    for (int j = 0; j < 5; ++j) S[i][j] = (f32x4){0.f, 0.f, 0.f, 0.f};
#pragma unroll
  for (int i = 0; i < 2; ++i)
#pragma unroll
    for (int j = 0; j < 5; ++j)
#pragma unroll
      for (int ks = 0; ks < 2; ++ks)
        S[i][j] = __builtin_amdgcn_mfma_f32_16x16x32_bf16(aq[i][ks], bk[j][ks],
                                                          S[i][j], 0, 0, 0);

  float rs[2][4] = {{0.f, 0.f, 0.f, 0.f}, {0.f, 0.f, 0.f, 0.f}};
#pragma unroll
  for (int i = 0; i < 2; ++i)
#pragma unroll
    for (int j = 0; j < 5; ++j) {
      const int col = j * 16 + mlane;
      const bool valid = col < 77;
#pragma unroll
      for (int r = 0; r < 4; ++r) {
        float e = valid ? __expf(S[i][j][r] * 0.125f) : 0.f;
        S[i][j][r] = e;
        rs[i][r] += e;
      }
    }
#pragma unroll
  for (int i = 0; i < 2; ++i)
#pragma unroll
    for (int r = 0; r < 4; ++r) {
      float v = rs[i][r];
      v += __shfl_xor(v, 1);
      v += __shfl_xor(v, 2);
      v += __shfl_xor(v, 4);
      v += __shfl_xor(v, 8);
      rs[i][r] = 1.f / v;
    }

#pragma unroll
  for (int i = 0; i < 2; ++i)
#pragma unroll
    for (int r = 0; r < 4; ++r) {
      const int row = wm + i * 16 + quad * 4 + r;
      u16* prow = Ps + row * 128;
#pragma unroll
      for (int j = 0; j < 5; ++j) {
        const int col = j * 16 + mlane;
        prow[(((col >> 3) + row) & 15) * 8 + (col & 7)] = f2bf(S[i][j][r]);
      }
      const int colz = 80 + mlane;
      prow[(((colz >> 3) + row) & 15) * 8 + (colz & 7)] = 0;
    }
  __syncthreads();

  const u16* vtb = vt_all + (size_t)blockIdx.x * 64 * 96;
  bf16x8 bv[4][3];
#pragma unroll
  for (int j = 0; j < 4; ++j)
#pragma unroll
    for (int kk = 0; kk < 3; ++kk)
      bv[j][kk] = *(const bf16x8*)(vtb + (j * 16 + mlane) * 96 + kk * 32 +
                                   quad * 8);

  f32x4 O[2][4];
#pragma unroll
  for (int i = 0; i < 2; ++i)
#pragma unroll
    for (int j = 0; j < 4; ++j) O[i][j] = (f32x4){0.f, 0.f, 0.f, 0.f};
#pragma unroll
  for (int i = 0; i < 2; ++i) {
    const int row = wm + i * 16 + mlane;
#pragma unroll
    for (int kk = 0; kk < 3; ++kk) {
      const bf16x8 ap = *(const bf16x8*)(
          Ps + row * 128 + (((kk * 4 + quad) + row) & 15) * 8);
#pragma unroll
      for (int j = 0; j < 4; ++j)
        O[i][j] = __builtin_amdgcn_mfma_f32_16x16x32_bf16(ap, bv[j][kk],
                                                          O[i][j], 0, 0, 0);
    }
  }

  u16* ob = o_all + ((size_t)(b * 4096 + n0 + wm)) * 512 + h * 64;
#pragma unroll
  for (int i = 0; i < 2; ++i)
#pragma unroll
    for (int j = 0; j < 4; ++j)
#pragma unroll
      for (int r = 0; r < 4; ++r) {
        const int rl = i * 16 + quad * 4 + r;
        ob[(size_t)rl * 512 + j * 16 + mlane] = f2bf(O[i][j][r] * rs[i][r]);
      }
}

extern "C" void kernel_launch(void* const* d_in, const int* in_sizes, int n_in,
                              void* d_out, int out_size, void* d_ws,
                              size_t ws_size, hipStream_t stream) {
  const float* x = (const float*)d_in[0];    // (16,4096,1024) fp32
  const float* ctx = (const float*)d_in[1];  // (16,77,768) fp32
  const float* Wq = (const float*)d_in[2];   // (1024,512)
  const float* Wk = (const float*)d_in[3];   // (768,512)
  const float* Wv = (const float*)d_in[4];   // (768,512)
  const float* Wo = (const float*)d_in[5];   // (512,1024)
  const float* bo = (const float*)d_in[6];   // (1024)

  char* p = (char*)d_ws;
  u16* WqT = (u16*)p;  p += (size_t)512 * 1024 * 2;
  u16* WkvT = (u16*)p; p += (size_t)1024 * 768 * 2;
  u16* WoT = (u16*)p;  p += (size_t)1024 * 512 * 2;
  u16* q_all = (u16*)p;    p += (size_t)65536 * 512 * 2;
  u16* kv_all = (u16*)p;   p += (size_t)1232 * 1024 * 2;
  u16* attn_out = (u16*)p; p += (size_t)65536 * 512 * 2;
  u16* vt_all = (u16*)p;   p += (size_t)128 * 64 * 96 * 2;

  wtrans<<<(1024 * 512 + 255) / 256, 256, 0, stream>>>(Wq, WqT, 1024, 512);
  wtrans<<<(768 * 512 + 255) / 256, 256, 0, stream>>>(Wk, WkvT, 768, 512);
  wtrans<<<(768 * 512 + 255) / 256, 256, 0, stream>>>(
      Wv, WkvT + (size_t)512 * 768, 768, 512);
  wtrans<<<(512 * 1024 + 255) / 256, 256, 0, stream>>>(Wo, WoT, 512, 1024);

  // q = x @ Wq : fp32 A (reg-staged cvt) -> bf16 C; 256x128 deep pipeline
  gemm_deep<true, false, 2><<<dim3(4, 256), 512, 0, stream>>>(
      x, WqT, q_all, nullptr, 1024, 512);
  // [k|v] = ctx @ [Wk|Wv] : fp32 A -> bf16 C (small; 128x128 path)
  gemm_bt<true, false><<<dim3(8, 10), 256, 0, stream>>>(
      ctx, WkvT, kv_all, nullptr, 1232, 768, 1024);
  // V^T for the PV MFMA
  vtrans<<<(128 * 64 * 96 + 255) / 256, 256, 0, stream>>>(kv_all, vt_all);
  // attention (MFMA)
  attn_mfma<<<dim3(128, 32), 256, 0, stream>>>(q_all, kv_all, vt_all,
                                               attn_out);
  // out = attn @ Wo + bo : bf16 A -> fp32 C + bias; 256x128 deep pipeline
  gemm_deep<false, true, 3><<<dim3(8, 256), 512, 0, stream>>>(
      attn_out, WoT, (void*)d_out, bo, 512, 1024);
}